// Round 3
// baseline (451.778 us; speedup 1.0000x reference)
//
#include <hip/hip_runtime.h>
#include <hip/hip_bf16.h>
#include <stdint.h>

// Problem constants: B=4, N=2048, D=1024, H=16, hd=64, NCTX=512
#define BATCH  4
#define NSEQ   2048
#define DMODEL 1024
#define NHEAD  16
#define HDIM   64
#define NCTXC  512

typedef unsigned short u16;
typedef __attribute__((ext_vector_type(8))) short bfrag;   // 8 bf16 = 4 VGPRs (MFMA A/B operand)
typedef __attribute__((ext_vector_type(4))) float facc;    // MFMA C/D operand

typedef __attribute__((address_space(3))) void lds_void;
typedef __attribute__((address_space(1))) void g_void;

__device__ __forceinline__ void gload16(const void* g, void* l) {
  __builtin_amdgcn_global_load_lds((const g_void*)g, (lds_void*)l, 16, 0, 0);
}

// bf16 conversion via HW v_cvt_pk_bf16_f32 (gfx950 has the instruction but no
// builtin — learn_hip m240). RNE rounding, same as the old bit-twiddle path.
__device__ __forceinline__ u16 f2bf(float f) {
  uint32_t r;
  asm("v_cvt_pk_bf16_f32 %0, %1, %1" : "=v"(r) : "v"(f));
  return (u16)r;
}

#if __has_builtin(__builtin_amdgcn_cvt_pk_bf16_f32)
__device__ __forceinline__ uint32_t pk2bf(float a, float b) {
  return __builtin_bit_cast(uint32_t, __builtin_amdgcn_cvt_pk_bf16_f32(a, b));
}
#else
__device__ __forceinline__ uint32_t pk2bf(float a, float b) {
  uint32_t r;
  asm("v_cvt_pk_bf16_f32 %0, %1, %2" : "=v"(r) : "v"(a), "v"(b));
  return r;
}
#endif

__device__ __forceinline__ float bf2f(u16 h) {
  union { uint32_t u; float f; } un;
  un.u = ((uint32_t)h) << 16;
  return un.f;
}

__device__ __forceinline__ float load_flex(const void* p, size_t idx, int isb) {
  return isb ? bf2f(((const u16*)p)[idx]) : ((const float*)p)[idx];
}

__device__ __forceinline__ uint4 pack8(float4 a, float4 b) {
  uint4 r;
  r.x = pk2bf(a.x, a.y);
  r.y = pk2bf(a.z, a.w);
  r.z = pk2bf(b.x, b.y);
  r.w = pk2bf(b.z, b.w);
  return r;
}

// ---------------------------------------------------------------- dtype detector
__global__ __launch_bounds__(256) void detect_kernel(const u16* __restrict__ xraw,
                                                     int* __restrict__ flag) {
  __shared__ int s_high, s_zero;
  if (threadIdx.x == 0) { s_high = 0; s_zero = 0; }
  __syncthreads();
  int h = 0, z = 0;
  for (int i = threadIdx.x; i < 4096; i += 256) {
    const u16 v = xraw[2 * i];
    const int e = (v >> 7) & 0xFF;
    if (e >= 0x90) h++;
    if (v == 0) z++;
  }
  atomicAdd(&s_high, h);
  atomicAdd(&s_zero, z);
  __syncthreads();
  if (threadIdx.x == 0) flag[0] = (s_high < 64 && s_zero < 2048) ? 1 : 0;
}

// ---------------------------------------------------------------- prep kernels

__global__ __launch_bounds__(256) void cast_x_kernel(const void* __restrict__ x,
                                                     u16* __restrict__ xb,
                                                     const int* __restrict__ flag) {
  const int isb = flag[0];
  const int i = blockIdx.x * 256 + threadIdx.x;
  if (isb) {
    ((uint4*)xb)[i] = ((const uint4*)x)[i];
  } else {
    const float4 f0 = ((const float4*)x)[2 * i];
    const float4 f1 = ((const float4*)x)[2 * i + 1];
    ((uint4*)xb)[i] = pack8(f0, f1);
  }
}

__global__ __launch_bounds__(256) void transpose_flex(const void* __restrict__ W,
                                                      u16* __restrict__ Wt,
                                                      int R, int C,
                                                      const int* __restrict__ flag) {
  __shared__ float tile[32][33];
  const int isb = flag[0];
  const int tx = threadIdx.x;
  const int ty = threadIdx.y;
  const int c0 = blockIdx.x * 32;
  const int r0 = blockIdx.y * 32;
#pragma unroll
  for (int j = 0; j < 32; j += 8)
    tile[ty + j][tx] = load_flex(W, (size_t)(r0 + ty + j) * C + c0 + tx, isb);
  __syncthreads();
#pragma unroll
  for (int j = 0; j < 32; j += 8)
    Wt[(size_t)(c0 + ty + j) * R + r0 + tx] = f2bf(tile[tx][ty + j]);
}

// fused small preps; cbias pre-scaled by log2(e) for exp2-domain softmax
__global__ __launch_bounds__(256) void prep_small(const void* __restrict__ b_in,
                                                  const void* __restrict__ b_out,
                                                  const void* __restrict__ ppr,
                                                  const void* __restrict__ trust,
                                                  const void* __restrict__ alpha_p,
                                                  const void* __restrict__ ts_p,
                                                  float* __restrict__ bin_f,
                                                  float* __restrict__ bout_f,
                                                  float* __restrict__ gate,
                                                  float* __restrict__ cbias,
                                                  const int* __restrict__ flag) {
  const int isb = flag[0];
  const int i = blockIdx.x * 256 + threadIdx.x;
  if (i < 3072) {
    bin_f[i] = load_flex(b_in, i, isb);
  } else if (i < 4096) {
    bout_f[i - 3072] = load_flex(b_out, i - 3072, isb);
  } else if (i < 4096 + BATCH * NCTXC) {
    const int j = i - 4096;
    const float ts = load_flex(ts_p, 0, isb), al = load_flex(alpha_p, 0, isb);
    gate[j]  = 1.0f / (1.0f + __expf(-ts * load_flex(trust, j, isb)));
    cbias[j] = -al * logf(fmaxf(load_flex(ppr, j, isb), 1e-8f)) * 1.44269504f;
  }
}

// ---------------------------------------------------------------- shared K-loop (m97 staging)
__device__ __forceinline__ void kloop_mfma(const u16* __restrict__ Ag,
                                           const u16* __restrict__ Bg,
                                           u16* As, u16* Bs,
                                           int tid, int wM, int wN, int l16, int quad,
                                           facc acc[4][4]) {
  char* ldsA = (char*)As + tid * 16;
  char* ldsB = (char*)Bs + tid * 16;
  for (int k0 = 0; k0 < 1024; k0 += 32) {
    __syncthreads();
    gload16(Ag + k0, ldsA);
    gload16(Ag + (size_t)64 * 1024 + k0, ldsA + 4096);
    gload16(Bg + k0, ldsB);
    gload16(Bg + (size_t)64 * 1024 + k0, ldsB + 4096);
    __syncthreads();

    bfrag af[4], bf[4];
#pragma unroll
    for (int i = 0; i < 4; ++i)
      af[i] = *(const bfrag*)(&As[(wM + i * 16 + l16) * 32 + quad * 8]);
#pragma unroll
    for (int j = 0; j < 4; ++j)
      bf[j] = *(const bfrag*)(&Bs[(wN + j * 16 + l16) * 32 + quad * 8]);
#pragma unroll
    for (int i = 0; i < 4; ++i)
#pragma unroll
      for (int j = 0; j < 4; ++j)
        acc[i][j] = __builtin_amdgcn_mfma_f32_16x16x32_bf16(af[i], bf[j], acc[i][j], 0, 0, 0);
  }
}

// ---------------------------------------------------------------- merged QK + V^T GEMM
__global__ __launch_bounds__(256) void gemm_qkvt(const u16* __restrict__ xb,
                                                 const u16* __restrict__ Wt,
                                                 const float* __restrict__ bin_f,
                                                 const float* __restrict__ gate,
                                                 u16* __restrict__ qk,
                                                 u16* __restrict__ Vtg) {
  __shared__ u16 As[128 * 32];
  __shared__ u16 Bs[128 * 32];
  const int tid  = threadIdx.x;
  const int w    = tid >> 6;
  const int lane = tid & 63;
  const int quad = lane >> 4;
  const int l16  = lane & 15;
  const int wM   = (w >> 1) * 64;
  const int wN   = (w & 1) * 64;
  const int id   = blockIdx.x;
  const int srow  = tid >> 2;
  const int spart = tid & 3;

  facc acc[4][4] = {};

  if (id < 1024) {
    const int bn = id & 15, bm = id >> 4;
    const u16* Ag = xb + (size_t)(bm * 128 + srow) * 1024 + spart * 8;
    const u16* Bg = Wt + (size_t)(bn * 128 + srow) * 1024 + spart * 8;
    kloop_mfma(Ag, Bg, As, Bs, tid, wM, wN, l16, quad, acc);

    const float qs = (bn < 8) ? 0.18033688f : 1.0f;
#pragma unroll
    for (int i = 0; i < 4; ++i) {
      const int grow0 = bm * 128 + wM + i * 16 + quad * 4;
#pragma unroll
      for (int j = 0; j < 4; ++j) {
        const int gcol = bn * 128 + wN + j * 16 + l16;
        const float bv = bin_f[gcol];
#pragma unroll
        for (int r = 0; r < 4; ++r)
          qk[(size_t)(grow0 + r) * 2048 + gcol] = f2bf((acc[i][j][r] + bv) * qs);
      }
    }
  } else {
    const int id2 = id - 1024;
    const int bn = id2 & 63, bm = id2 >> 6;
    const u16* Ag = Wt + (size_t)2048 * 1024 + (size_t)(bm * 128 + srow) * 1024 + spart * 8;
    const u16* Bg = xb + (size_t)(bn * 128 + srow) * 1024 + spart * 8;
    kloop_mfma(Ag, Bg, As, Bs, tid, wM, wN, l16, quad, acc);

#pragma unroll
    for (int i = 0; i < 4; ++i) {
      const int grow0 = bm * 128 + wM + i * 16 + quad * 4;
      const int h   = grow0 >> 6;
      const int dd0 = grow0 & 63;
#pragma unroll
      for (int j = 0; j < 4; ++j) {
        const int gcol = bn * 128 + wN + j * 16 + l16;
        const int bb  = gcol >> 11;
        const int tok = gcol & (NSEQ - 1);
        const float gl = (tok < NCTXC) ? gate[bb * NCTXC + tok] : 1.0f;
        u16* dst = &Vtg[((size_t)((bb * NHEAD + h) * HDIM + dd0)) * NSEQ + tok];
#pragma unroll
        for (int r = 0; r < 4; ++r)
          dst[(size_t)r * NSEQ] = f2bf((acc[i][j][r] + bin_f[2 * DMODEL + grow0 + r]) * gl);
      }
    }
  }
}

// ---------------------------------------------------------------- output GEMM (m97 staging)
__global__ __launch_bounds__(256) void gemm_out(const u16* __restrict__ A,
                                                const u16* __restrict__ Bt,
                                                const float* __restrict__ biasf,
                                                void* __restrict__ Cout,
                                                const int* __restrict__ flag) {
  __shared__ u16 As[128 * 32];
  __shared__ u16 Bs[128 * 32];
  const int isb  = flag[0];
  const int tid  = threadIdx.x;
  const int w    = tid >> 6;
  const int lane = tid & 63;
  const int quad = lane >> 4;
  const int l16  = lane & 15;
  const int wM   = (w >> 1) * 64;
  const int wN   = (w & 1) * 64;
  const int bm   = blockIdx.y;
  const int bn   = blockIdx.x;
  const int srow  = tid >> 2;
  const int spart = tid & 3;

  facc acc[4][4] = {};
  const u16* Ag = A + (size_t)(bm * 128 + srow) * 2048 + spart * 8;
  const u16* Bg = Bt + (size_t)(bn * 128 + srow) * 1024 + spart * 8;
  char* ldsA = (char*)As + tid * 16;
  char* ldsB = (char*)Bs + tid * 16;

  for (int k0 = 0; k0 < 1024; k0 += 32) {
    __syncthreads();
    gload16(Ag + k0, ldsA);
    gload16(Ag + (size_t)64 * 2048 + k0, ldsA + 4096);
    gload16(Bg + k0, ldsB);
    gload16(Bg + (size_t)64 * 1024 + k0, ldsB + 4096);
    __syncthreads();

    bfrag af[4], bf[4];
#pragma unroll
    for (int i = 0; i < 4; ++i)
      af[i] = *(const bfrag*)(&As[(wM + i * 16 + l16) * 32 + quad * 8]);
#pragma unroll
    for (int j = 0; j < 4; ++j)
      bf[j] = *(const bfrag*)(&Bs[(wN + j * 16 + l16) * 32 + quad * 8]);
#pragma unroll
    for (int i = 0; i < 4; ++i)
#pragma unroll
      for (int j = 0; j < 4; ++j)
        acc[i][j] = __builtin_amdgcn_mfma_f32_16x16x32_bf16(af[i], bf[j], acc[i][j], 0, 0, 0);
  }

#pragma unroll
  for (int i = 0; i < 4; ++i) {
    const int grow0 = bm * 128 + wM + i * 16 + quad * 4;
#pragma unroll
    for (int j = 0; j < 4; ++j) {
      const int gcol = bn * 128 + wN + j * 16 + l16;
      const float bv = biasf[gcol];
#pragma unroll
      for (int r = 0; r < 4; ++r) {
        const float v = acc[i][j][r] + bv;
        if (isb) ((u16*)Cout)[(size_t)(grow0 + r) * 1024 + gcol] = f2bf(v);
        else     ((float*)Cout)[(size_t)(grow0 + r) * 1024 + gcol] = v;
      }
    }
  }
}

// ---------------------------------------------------------------- flash attention
// R3: BARRIER-FREE. K/V fragments are loaded directly from global (L2/L3-
// resident; each lane's fragment is a contiguous 16B dwordx4 — the LDS indices
// transcribed 1:1 to global addresses), register-double-buffered one tile
// ahead. No __syncthreads in the loop; waves free-run. Ps stays in LDS
// (per-wave-private; same-wave DS in-order gives RAW for free).
__device__ __forceinline__ void load_kf(const u16* __restrict__ kb, int t,
                                        int l16, int quad, bfrag ak[4][2]) {
#pragma unroll
  for (int nt = 0; nt < 4; ++nt) {
    const u16* p = kb + (size_t)(t * 64 + nt * 16 + l16) * 2048 + quad * 8;
    ak[nt][0] = *(const bfrag*)(p);
    ak[nt][1] = *(const bfrag*)(p + 32);
  }
}

__device__ __forceinline__ void load_vf(const u16* __restrict__ vb, int t,
                                        int l16, int quad, bfrag av[4][2]) {
#pragma unroll
  for (int dt = 0; dt < 4; ++dt) {
    const u16* p = vb + (size_t)(dt * 16 + l16) * NSEQ + t * 64 + quad * 8;
    av[dt][0] = *(const bfrag*)(p);
    av[dt][1] = *(const bfrag*)(p + 32);
  }
}

__device__ __forceinline__ void attn_tile(int t, int b,
                                          const bfrag (&ak)[4][2],
                                          const bfrag (&av)[4][2],
                                          const bfrag (&bq)[2][2],
                                          u16* const (&psw)[2],
                                          const float* __restrict__ cbias,
                                          facc (&den)[2], facc (&o)[2][4],
                                          int l16, int quad) {
  // per-tile column bias as MFMA C-init (kv-dependent only, shared by both qs)
  facc zb[4];
  if (t < 8) {
    const float* cb = cbias + b * NCTXC + t * 64 + quad * 4;
#pragma unroll
    for (int nt = 0; nt < 4; ++nt) zb[nt] = *(const facc*)(cb + nt * 16);
  } else {
#pragma unroll
    for (int nt = 0; nt < 4; ++nt) zb[nt] = (facc){};
  }

  // QK(qs) -> exp2 -> Ps write, both subtiles
#pragma unroll
  for (int qs = 0; qs < 2; ++qs) {
    facc s[4];
    __builtin_amdgcn_s_setprio(1);
#pragma unroll
    for (int nt = 0; nt < 4; ++nt) {
      facc z = zb[nt];
      z = __builtin_amdgcn_mfma_f32_16x16x32_bf16(ak[nt][0], bq[qs][0], z, 0, 0, 0);
      s[nt] = __builtin_amdgcn_mfma_f32_16x16x32_bf16(ak[nt][1], bq[qs][1], z, 0, 0, 0);
    }
    __builtin_amdgcn_s_setprio(0);

#pragma unroll
    for (int nt = 0; nt < 4; ++nt)
#pragma unroll
      for (int r = 0; r < 4; ++r)
        s[nt][r] = __builtin_amdgcn_exp2f(s[nt][r]);

#pragma unroll
    for (int nt = 0; nt < 4; ++nt) {
      uint2 pk;
      pk.x = pk2bf(s[nt][0], s[nt][1]);
      pk.y = pk2bf(s[nt][2], s[nt][3]);
      *(uint2*)(&psw[qs][l16 * 72 + nt * 16 + quad * 4]) = pk;
    }
  }

  // ones A-fragment for the denominator MFMA: D[i][j] = sum_k P[k][j]
  bfrag ones;
#pragma unroll
  for (int i = 0; i < 8; ++i) ones[i] = (short)0x3F80;   // bf16 1.0

  // P reads + PV + denominator MFMA, both subtiles
  // (DS in-order per wave => Ps writes above complete before these reads)
#pragma unroll
  for (int qs = 0; qs < 2; ++qs) {
    const bfrag bp0 = *(const bfrag*)(&psw[qs][l16 * 72 + quad * 8]);
    const bfrag bp1 = *(const bfrag*)(&psw[qs][l16 * 72 + 32 + quad * 8]);
    __builtin_amdgcn_s_setprio(1);
#pragma unroll
    for (int dt = 0; dt < 4; ++dt) {
      o[qs][dt] = __builtin_amdgcn_mfma_f32_16x16x32_bf16(av[dt][0], bp0, o[qs][dt], 0, 0, 0);
      o[qs][dt] = __builtin_amdgcn_mfma_f32_16x16x32_bf16(av[dt][1], bp1, o[qs][dt], 0, 0, 0);
    }
    den[qs] = __builtin_amdgcn_mfma_f32_16x16x32_bf16(ones, bp0, den[qs], 0, 0, 0);
    den[qs] = __builtin_amdgcn_mfma_f32_16x16x32_bf16(ones, bp1, den[qs], 0, 0, 0);
    __builtin_amdgcn_s_setprio(0);
  }
}

__global__ __launch_bounds__(256) void attn_kernel(u16* __restrict__ qk,
                                                   const u16* __restrict__ vtg,
                                                   const float* __restrict__ cbias) {
  const int id    = blockIdx.x;             // 0..1023
  const int chunk = id >> 3;
  const int qt    = chunk & 15;
  const int hg    = (id & 7) | ((chunk >> 4) << 3);
  const int h     = hg & 15;
  const int b     = hg >> 4;

  __shared__ u16 Ps[8][16 * 72];     // [wave*2+qs] private P slices

  const int tid  = threadIdx.x;
  const int w    = tid >> 6;
  const int lane = tid & 63;
  const int quad = lane >> 4;
  const int l16  = lane & 15;

  bfrag bq[2][2];
#pragma unroll
  for (int qs = 0; qs < 2; ++qs) {
    const u16* qrow = qk + (size_t)(b * NSEQ + qt * 128 + (w * 2 + qs) * 16 + l16) * 2048 + h * HDIM;
    bq[qs][0] = *(const bfrag*)(qrow + quad * 8);
    bq[qs][1] = *(const bfrag*)(qrow + 32 + quad * 8);
  }

  facc den[2] = {};                  // per-qs denominator accumulators
  facc o[2][4] = {};

  const u16* kb = qk + (size_t)(b * NSEQ) * 2048 + DMODEL + h * HDIM;
  const u16* vb = vtg + (size_t)((b * NHEAD + h) * HDIM) * NSEQ;
  u16* const psw[2] = { Ps[w * 2], Ps[w * 2 + 1] };

  // register double-buffered K/V fragments, one tile of prefetch lead
  bfrag akA[4][2], avA[4][2], akB[4][2], avB[4][2];
  load_kf(kb, 0, l16, quad, akA);
  load_vf(vb, 0, l16, quad, avA);

  for (int t = 0; t < NSEQ / 64; t += 2) {
    load_kf(kb, t + 1, l16, quad, akB);
    load_vf(vb, t + 1, l16, quad, avB);
    attn_tile(t, b, akA, avA, bq, psw, cbias, den, o, l16, quad);

    const int tn = (t + 2 < NSEQ / 64) ? t + 2 : NSEQ / 64 - 1;
    load_kf(kb, tn, l16, quad, akA);
    load_vf(vb, tn, l16, quad, avA);
    attn_tile(t + 1, b, akB, avB, bq, psw, cbias, den, o, l16, quad);
  }

  // epilogue: every lane already holds its q-column's denominator (col=l16)
#pragma unroll
  for (int qs = 0; qs < 2; ++qs) {
    const float inv = 1.0f / den[qs][0];
    u16* orow = qk + (size_t)(b * NSEQ + qt * 128 + (w * 2 + qs) * 16 + l16) * 2048 + h * HDIM;
#pragma unroll
    for (int dt = 0; dt < 4; ++dt) {
      uint2 st;
      st.x = pk2bf(o[qs][dt][0] * inv, o[qs][dt][1] * inv);
      st.y = pk2bf(o[qs][dt][2] * inv, o[qs][dt][3] * inv);
      *(uint2*)(orow + dt * 16 + quad * 4) = st;
    }
  }
}

// ---------------------------------------------------------------- launch

extern "C" void kernel_launch(void* const* d_in, const int* in_sizes, int n_in,
                              void* d_out, int out_size, void* d_ws, size_t ws_size,
                              hipStream_t stream) {
  const void* x          = d_in[0];
  const void* ctx_ppr    = d_in[1];
  const void* ctx_trust  = d_in[2];
  const void* W_in       = d_in[3];
  const void* b_in       = d_in[4];
  const void* W_out      = d_in[5];
  const void* b_out      = d_in[6];
  const void* lppr_alpha = d_in[7];
  const void* tscale     = d_in[8];

  char* ws = (char*)d_ws;
  u16* Wt    = (u16*)ws;  ws += (size_t)3072 * 1024 * 2;    //  6 MB  W_in^T bf16
  u16* WoT   = (u16*)ws;  ws += (size_t)1024 * 1024 * 2;    //  2 MB  W_out^T bf16
  u16* qk    = (u16*)ws;  ws += (size_t)8192 * 2048 * 2;    // 32 MB  [Q|K]; attn-out overwrites Q-plane
  u16* Vtg   = (u16*)ws;  ws += (size_t)64 * 64 * 2048 * 2; // 16 MB  gated V^T [b*16+h][d][n]
  u16* xb    = (u16*)ws;  ws += (size_t)8192 * 1024 * 2;    // 16 MB  x as bf16
  float* bin_f  = (float*)ws; ws += 3072 * 4;
  float* bout_f = (float*)ws; ws += 1024 * 4;
  float* gate   = (float*)ws; ws += (size_t)BATCH * NCTXC * 4;
  float* cbias  = (float*)ws; ws += (size_t)BATCH * NCTXC * 4;
  int*   flag   = (int*)ws;   ws += 64;

  detect_kernel<<<dim3(1), dim3(256), 0, stream>>>((const u16*)x, flag);
  cast_x_kernel<<<dim3(4096), dim3(256), 0, stream>>>(x, xb, flag);
  transpose_flex<<<dim3(96, 32), dim3(32, 8), 0, stream>>>(W_in, Wt, 1024, 3072, flag);
  transpose_flex<<<dim3(32, 32), dim3(32, 8), 0, stream>>>(W_out, WoT, 1024, 1024, flag);
  prep_small<<<dim3(24), dim3(256), 0, stream>>>(b_in, b_out, ctx_ppr, ctx_trust,
                                                 lppr_alpha, tscale,
                                                 bin_f, bout_f, gate, cbias, flag);
  // merged QK GEMM (1024 blocks) + V^T GEMM (512 blocks)
  gemm_qkvt<<<dim3(1536), dim3(256), 0, stream>>>(xb, Wt, bin_f, gate, qk, Vtg);
  // fused biased attention (128-q, XCD-swizzled, barrier-free, reg-dbuf K/V)
  attn_kernel<<<dim3(1024), dim3(256), 0, stream>>>(qk, Vtg, cbias);
  // output GEMM: [8192x1024 (lda 2048)] @ [1024x1024] (+b_out) -> d_out
  gemm_out<<<dim3(8, 64), dim3(256), 0, stream>>>(qk, WoT, bout_f, d_out, flag);
}

// Round 4
// 301.150 us; speedup vs baseline: 1.5002x; 1.5002x over previous
//
#include <hip/hip_runtime.h>
#include <hip/hip_bf16.h>
#include <stdint.h>

// Problem constants: B=4, N=2048, D=1024, H=16, hd=64, NCTX=512
#define BATCH  4
#define NSEQ   2048
#define DMODEL 1024
#define NHEAD  16
#define HDIM   64
#define NCTXC  512

typedef unsigned short u16;
typedef __attribute__((ext_vector_type(8))) short bfrag;   // 8 bf16 = 4 VGPRs (MFMA A/B operand)
typedef __attribute__((ext_vector_type(4))) float facc;    // MFMA C/D operand

typedef __attribute__((address_space(3))) void lds_void;
typedef __attribute__((address_space(1))) void g_void;

__device__ __forceinline__ void gload16(const void* g, void* l) {
  __builtin_amdgcn_global_load_lds((const g_void*)g, (lds_void*)l, 16, 0, 0);
}

// bf16 conversion via HW v_cvt_pk_bf16_f32 (gfx950 has the instruction but no
// builtin — learn_hip m240). RNE rounding, same as the old bit-twiddle path.
__device__ __forceinline__ u16 f2bf(float f) {
  uint32_t r;
  asm("v_cvt_pk_bf16_f32 %0, %1, %1" : "=v"(r) : "v"(f));
  return (u16)r;
}

#if __has_builtin(__builtin_amdgcn_cvt_pk_bf16_f32)
__device__ __forceinline__ uint32_t pk2bf(float a, float b) {
  return __builtin_bit_cast(uint32_t, __builtin_amdgcn_cvt_pk_bf16_f32(a, b));
}
#else
__device__ __forceinline__ uint32_t pk2bf(float a, float b) {
  uint32_t r;
  asm("v_cvt_pk_bf16_f32 %0, %1, %2" : "=v"(r) : "v"(a), "v"(b));
  return r;
}
#endif

__device__ __forceinline__ float bf2f(u16 h) {
  union { uint32_t u; float f; } un;
  un.u = ((uint32_t)h) << 16;
  return un.f;
}

__device__ __forceinline__ float load_flex(const void* p, size_t idx, int isb) {
  return isb ? bf2f(((const u16*)p)[idx]) : ((const float*)p)[idx];
}

__device__ __forceinline__ uint4 pack8(float4 a, float4 b) {
  uint4 r;
  r.x = pk2bf(a.x, a.y);
  r.y = pk2bf(a.z, a.w);
  r.z = pk2bf(b.x, b.y);
  r.w = pk2bf(b.z, b.w);
  return r;
}

// ---------------------------------------------------------------- dtype detector
__global__ __launch_bounds__(256) void detect_kernel(const u16* __restrict__ xraw,
                                                     int* __restrict__ flag) {
  __shared__ int s_high, s_zero;
  if (threadIdx.x == 0) { s_high = 0; s_zero = 0; }
  __syncthreads();
  int h = 0, z = 0;
  for (int i = threadIdx.x; i < 4096; i += 256) {
    const u16 v = xraw[2 * i];
    const int e = (v >> 7) & 0xFF;
    if (e >= 0x90) h++;
    if (v == 0) z++;
  }
  atomicAdd(&s_high, h);
  atomicAdd(&s_zero, z);
  __syncthreads();
  if (threadIdx.x == 0) flag[0] = (s_high < 64 && s_zero < 2048) ? 1 : 0;
}

// ---------------------------------------------------------------- prep kernels

__global__ __launch_bounds__(256) void cast_x_kernel(const void* __restrict__ x,
                                                     u16* __restrict__ xb,
                                                     const int* __restrict__ flag) {
  const int isb = flag[0];
  const int i = blockIdx.x * 256 + threadIdx.x;
  if (isb) {
    ((uint4*)xb)[i] = ((const uint4*)x)[i];
  } else {
    const float4 f0 = ((const float4*)x)[2 * i];
    const float4 f1 = ((const float4*)x)[2 * i + 1];
    ((uint4*)xb)[i] = pack8(f0, f1);
  }
}

__global__ __launch_bounds__(256) void transpose_flex(const void* __restrict__ W,
                                                      u16* __restrict__ Wt,
                                                      int R, int C,
                                                      const int* __restrict__ flag) {
  __shared__ float tile[32][33];
  const int isb = flag[0];
  const int tx = threadIdx.x;
  const int ty = threadIdx.y;
  const int c0 = blockIdx.x * 32;
  const int r0 = blockIdx.y * 32;
#pragma unroll
  for (int j = 0; j < 32; j += 8)
    tile[ty + j][tx] = load_flex(W, (size_t)(r0 + ty + j) * C + c0 + tx, isb);
  __syncthreads();
#pragma unroll
  for (int j = 0; j < 32; j += 8)
    Wt[(size_t)(c0 + ty + j) * R + r0 + tx] = f2bf(tile[tx][ty + j]);
}

// fused small preps; cbias pre-scaled by log2(e) for exp2-domain softmax
__global__ __launch_bounds__(256) void prep_small(const void* __restrict__ b_in,
                                                  const void* __restrict__ b_out,
                                                  const void* __restrict__ ppr,
                                                  const void* __restrict__ trust,
                                                  const void* __restrict__ alpha_p,
                                                  const void* __restrict__ ts_p,
                                                  float* __restrict__ bin_f,
                                                  float* __restrict__ bout_f,
                                                  float* __restrict__ gate,
                                                  float* __restrict__ cbias,
                                                  const int* __restrict__ flag) {
  const int isb = flag[0];
  const int i = blockIdx.x * 256 + threadIdx.x;
  if (i < 3072) {
    bin_f[i] = load_flex(b_in, i, isb);
  } else if (i < 4096) {
    bout_f[i - 3072] = load_flex(b_out, i - 3072, isb);
  } else if (i < 4096 + BATCH * NCTXC) {
    const int j = i - 4096;
    const float ts = load_flex(ts_p, 0, isb), al = load_flex(alpha_p, 0, isb);
    gate[j]  = 1.0f / (1.0f + __expf(-ts * load_flex(trust, j, isb)));
    cbias[j] = -al * logf(fmaxf(load_flex(ppr, j, isb), 1e-8f)) * 1.44269504f;
  }
}

// ---------------------------------------------------------------- shared K-loop (m97 staging)
__device__ __forceinline__ void kloop_mfma(const u16* __restrict__ Ag,
                                           const u16* __restrict__ Bg,
                                           u16* As, u16* Bs,
                                           int tid, int wM, int wN, int l16, int quad,
                                           facc acc[4][4]) {
  char* ldsA = (char*)As + tid * 16;
  char* ldsB = (char*)Bs + tid * 16;
  for (int k0 = 0; k0 < 1024; k0 += 32) {
    __syncthreads();
    gload16(Ag + k0, ldsA);
    gload16(Ag + (size_t)64 * 1024 + k0, ldsA + 4096);
    gload16(Bg + k0, ldsB);
    gload16(Bg + (size_t)64 * 1024 + k0, ldsB + 4096);
    __syncthreads();

    bfrag af[4], bf[4];
#pragma unroll
    for (int i = 0; i < 4; ++i)
      af[i] = *(const bfrag*)(&As[(wM + i * 16 + l16) * 32 + quad * 8]);
#pragma unroll
    for (int j = 0; j < 4; ++j)
      bf[j] = *(const bfrag*)(&Bs[(wN + j * 16 + l16) * 32 + quad * 8]);
#pragma unroll
    for (int i = 0; i < 4; ++i)
#pragma unroll
      for (int j = 0; j < 4; ++j)
        acc[i][j] = __builtin_amdgcn_mfma_f32_16x16x32_bf16(af[i], bf[j], acc[i][j], 0, 0, 0);
  }
}

// ---------------------------------------------------------------- merged QK + V^T GEMM
__global__ __launch_bounds__(256) void gemm_qkvt(const u16* __restrict__ xb,
                                                 const u16* __restrict__ Wt,
                                                 const float* __restrict__ bin_f,
                                                 const float* __restrict__ gate,
                                                 u16* __restrict__ qk,
                                                 u16* __restrict__ Vtg) {
  __shared__ u16 As[128 * 32];
  __shared__ u16 Bs[128 * 32];
  const int tid  = threadIdx.x;
  const int w    = tid >> 6;
  const int lane = tid & 63;
  const int quad = lane >> 4;
  const int l16  = lane & 15;
  const int wM   = (w >> 1) * 64;
  const int wN   = (w & 1) * 64;
  const int id   = blockIdx.x;
  const int srow  = tid >> 2;
  const int spart = tid & 3;

  facc acc[4][4] = {};

  if (id < 1024) {
    const int bn = id & 15, bm = id >> 4;
    const u16* Ag = xb + (size_t)(bm * 128 + srow) * 1024 + spart * 8;
    const u16* Bg = Wt + (size_t)(bn * 128 + srow) * 1024 + spart * 8;
    kloop_mfma(Ag, Bg, As, Bs, tid, wM, wN, l16, quad, acc);

    const float qs = (bn < 8) ? 0.18033688f : 1.0f;
#pragma unroll
    for (int i = 0; i < 4; ++i) {
      const int grow0 = bm * 128 + wM + i * 16 + quad * 4;
#pragma unroll
      for (int j = 0; j < 4; ++j) {
        const int gcol = bn * 128 + wN + j * 16 + l16;
        const float bv = bin_f[gcol];
#pragma unroll
        for (int r = 0; r < 4; ++r)
          qk[(size_t)(grow0 + r) * 2048 + gcol] = f2bf((acc[i][j][r] + bv) * qs);
      }
    }
  } else {
    const int id2 = id - 1024;
    const int bn = id2 & 63, bm = id2 >> 6;
    const u16* Ag = Wt + (size_t)2048 * 1024 + (size_t)(bm * 128 + srow) * 1024 + spart * 8;
    const u16* Bg = xb + (size_t)(bn * 128 + srow) * 1024 + spart * 8;
    kloop_mfma(Ag, Bg, As, Bs, tid, wM, wN, l16, quad, acc);

#pragma unroll
    for (int i = 0; i < 4; ++i) {
      const int grow0 = bm * 128 + wM + i * 16 + quad * 4;
      const int h   = grow0 >> 6;
      const int dd0 = grow0 & 63;
#pragma unroll
      for (int j = 0; j < 4; ++j) {
        const int gcol = bn * 128 + wN + j * 16 + l16;
        const int bb  = gcol >> 11;
        const int tok = gcol & (NSEQ - 1);
        const float gl = (tok < NCTXC) ? gate[bb * NCTXC + tok] : 1.0f;
        u16* dst = &Vtg[((size_t)((bb * NHEAD + h) * HDIM + dd0)) * NSEQ + tok];
#pragma unroll
        for (int r = 0; r < 4; ++r)
          dst[(size_t)r * NSEQ] = f2bf((acc[i][j][r] + bin_f[2 * DMODEL + grow0 + r]) * gl);
      }
    }
  }
}

// ---------------------------------------------------------------- output GEMM (m97 staging)
__global__ __launch_bounds__(256) void gemm_out(const u16* __restrict__ A,
                                                const u16* __restrict__ Bt,
                                                const float* __restrict__ biasf,
                                                void* __restrict__ Cout,
                                                const int* __restrict__ flag) {
  __shared__ u16 As[128 * 32];
  __shared__ u16 Bs[128 * 32];
  const int isb  = flag[0];
  const int tid  = threadIdx.x;
  const int w    = tid >> 6;
  const int lane = tid & 63;
  const int quad = lane >> 4;
  const int l16  = lane & 15;
  const int wM   = (w >> 1) * 64;
  const int wN   = (w & 1) * 64;
  const int bm   = blockIdx.y;
  const int bn   = blockIdx.x;
  const int srow  = tid >> 2;
  const int spart = tid & 3;

  facc acc[4][4] = {};
  const u16* Ag = A + (size_t)(bm * 128 + srow) * 2048 + spart * 8;
  const u16* Bg = Bt + (size_t)(bn * 128 + srow) * 1024 + spart * 8;
  char* ldsA = (char*)As + tid * 16;
  char* ldsB = (char*)Bs + tid * 16;

  for (int k0 = 0; k0 < 1024; k0 += 32) {
    __syncthreads();
    gload16(Ag + k0, ldsA);
    gload16(Ag + (size_t)64 * 2048 + k0, ldsA + 4096);
    gload16(Bg + k0, ldsB);
    gload16(Bg + (size_t)64 * 1024 + k0, ldsB + 4096);
    __syncthreads();

    bfrag af[4], bf[4];
#pragma unroll
    for (int i = 0; i < 4; ++i)
      af[i] = *(const bfrag*)(&As[(wM + i * 16 + l16) * 32 + quad * 8]);
#pragma unroll
    for (int j = 0; j < 4; ++j)
      bf[j] = *(const bfrag*)(&Bs[(wN + j * 16 + l16) * 32 + quad * 8]);
#pragma unroll
    for (int i = 0; i < 4; ++i)
#pragma unroll
      for (int j = 0; j < 4; ++j)
        acc[i][j] = __builtin_amdgcn_mfma_f32_16x16x32_bf16(af[i], bf[j], acc[i][j], 0, 0, 0);
  }

#pragma unroll
  for (int i = 0; i < 4; ++i) {
    const int grow0 = bm * 128 + wM + i * 16 + quad * 4;
#pragma unroll
    for (int j = 0; j < 4; ++j) {
      const int gcol = bn * 128 + wN + j * 16 + l16;
      const float bv = biasf[gcol];
#pragma unroll
      for (int r = 0; r < 4; ++r) {
        const float v = acc[i][j][r] + bv;
        if (isb) ((u16*)Cout)[(size_t)(grow0 + r) * 1024 + gcol] = f2bf(v);
        else     ((float*)Cout)[(size_t)(grow0 + r) * 1024 + gcol] = v;
      }
    }
  }
}

// ---------------------------------------------------------------- flash attention
// R4: back to R2's LDS-staged K/V (R3 proved staging is load-bearing), but the
// P LDS round-trip is GONE. MFMA k-order freedom: PV's B-fragment k-slot j maps
// to kv = (j>>2)*16 + quad*4 + (j&3) — exactly where the QK output s[nt][r]
// already sits in registers. bp = packed s[] in place (no cross-lane movement,
// no Ps buffer). The matching V^T A-fragment uses the same k-map: two 8B LDS
// reads per half (cols quad*4 and 16+quad*4) — same bytes as the old b128.
__global__ __launch_bounds__(256) void attn_kernel(u16* __restrict__ qk,
                                                   const u16* __restrict__ vtg,
                                                   const float* __restrict__ cbias) {
  const int id    = blockIdx.x;             // 0..1023
  const int chunk = id >> 3;
  const int qt    = chunk & 15;
  const int hg    = (id & 7) | ((chunk >> 4) << 3);
  const int h     = hg & 15;
  const int b     = hg >> 4;

  __shared__ u16 Ks[64 * 72];        // K tile [kv][d]
  __shared__ u16 Vt[64 * 72];        // V^T tile [d][kv]

  const int tid  = threadIdx.x;
  const int w    = tid >> 6;
  const int lane = tid & 63;
  const int quad = lane >> 4;
  const int l16  = lane & 15;
  const int srow = tid >> 2;
  const int spart = tid & 3;

  bfrag bq[2][2];
#pragma unroll
  for (int qs = 0; qs < 2; ++qs) {
    const u16* qrow = qk + (size_t)(b * NSEQ + qt * 128 + (w * 2 + qs) * 16 + l16) * 2048 + h * HDIM;
    bq[qs][0] = *(const bfrag*)(qrow + quad * 8);
    bq[qs][1] = *(const bfrag*)(qrow + 32 + quad * 8);
  }

  // ones A-fragment for the denominator MFMA (k-order invariant)
  bfrag ones;
#pragma unroll
  for (int i = 0; i < 8; ++i) ones[i] = (short)0x3F80;   // bf16 1.0

  facc den[2] = {};                  // per-qs denominator accumulators
  facc o[2][4] = {};

  const u16* kst = qk + (size_t)(b * NSEQ) * 2048 + DMODEL + h * HDIM;
  const u16* vst = vtg + (size_t)((b * NHEAD + h) * HDIM + srow) * NSEQ;

  uint4 pk0, pk1, pv0, pv1;
  {
    const u16* ks = kst + (size_t)srow * 2048 + spart * 16;
    pk0 = *(const uint4*)ks;
    pk1 = *(const uint4*)(ks + 8);
    const u16* vs = vst + spart * 16;
    pv0 = *(const uint4*)vs;
    pv1 = *(const uint4*)(vs + 8);
  }

  for (int t = 0; t < NSEQ / 64; ++t) {
    __syncthreads();
    *(uint4*)(&Ks[srow * 72 + spart * 16])     = pk0;
    *(uint4*)(&Ks[srow * 72 + spart * 16 + 8]) = pk1;
    *(uint4*)(&Vt[srow * 72 + spart * 16])     = pv0;
    *(uint4*)(&Vt[srow * 72 + spart * 16 + 8]) = pv1;
    __syncthreads();

    // prefetch next K/V tile
    {
      const int tn = (t < NSEQ / 64 - 1) ? t + 1 : t;
      const u16* ks = kst + (size_t)(tn * 64 + srow) * 2048 + spart * 16;
      pk0 = *(const uint4*)ks;
      pk1 = *(const uint4*)(ks + 8);
      const u16* vs = vst + tn * 64 + spart * 16;
      pv0 = *(const uint4*)vs;
      pv1 = *(const uint4*)(vs + 8);
    }

    // K fragments (contiguous b128, as before)
    bfrag ak[4][2];
#pragma unroll
    for (int nt = 0; nt < 4; ++nt) {
      ak[nt][0] = *(const bfrag*)(&Ks[(nt * 16 + l16) * 72 + quad * 8]);
      ak[nt][1] = *(const bfrag*)(&Ks[(nt * 16 + l16) * 72 + 32 + quad * 8]);
    }

    // V fragments in the bp-matching k-order: element j of av[dt][half] is
    // V^T[dt*16+l16][ half*32 + (j>>2)*16 + quad*4 + (j&3) ]
    bfrag av[4][2];
#pragma unroll
    for (int dt = 0; dt < 4; ++dt) {
      const u16* vr = &Vt[(dt * 16 + l16) * 72];
#pragma unroll
      for (int half = 0; half < 2; ++half) {
        union { bfrag f; uint2 u2[2]; } un;
        un.u2[0] = *(const uint2*)(vr + half * 32 + quad * 4);
        un.u2[1] = *(const uint2*)(vr + half * 32 + 16 + quad * 4);
        av[dt][half] = un.f;
      }
    }

    // per-tile column bias as MFMA C-init (kv-dependent only, shared by both qs)
    facc zb[4];
    if (t < 8) {
      const float* cb = cbias + b * NCTXC + t * 64 + quad * 4;
#pragma unroll
      for (int nt = 0; nt < 4; ++nt) zb[nt] = *(const facc*)(cb + nt * 16);
    } else {
#pragma unroll
      for (int nt = 0; nt < 4; ++nt) zb[nt] = (facc){};
    }

    // per qs: QK -> exp2 -> in-register pack -> PV + den, all register-resident
#pragma unroll
    for (int qs = 0; qs < 2; ++qs) {
      facc s[4];
      __builtin_amdgcn_s_setprio(1);
#pragma unroll
      for (int nt = 0; nt < 4; ++nt) {
        facc z = zb[nt];
        z = __builtin_amdgcn_mfma_f32_16x16x32_bf16(ak[nt][0], bq[qs][0], z, 0, 0, 0);
        s[nt] = __builtin_amdgcn_mfma_f32_16x16x32_bf16(ak[nt][1], bq[qs][1], z, 0, 0, 0);
      }
      __builtin_amdgcn_s_setprio(0);

#pragma unroll
      for (int nt = 0; nt < 4; ++nt)
#pragma unroll
        for (int r = 0; r < 4; ++r)
          s[nt][r] = __builtin_amdgcn_exp2f(s[nt][r]);

      // bp[half] slot j holds P[kv = half*32 + (j>>2)*16 + quad*4 + (j&3)][l16]
      union { bfrag f; uint32_t wrd[4]; } bp0, bp1;
      bp0.wrd[0] = pk2bf(s[0][0], s[0][1]);
      bp0.wrd[1] = pk2bf(s[0][2], s[0][3]);
      bp0.wrd[2] = pk2bf(s[1][0], s[1][1]);
      bp0.wrd[3] = pk2bf(s[1][2], s[1][3]);
      bp1.wrd[0] = pk2bf(s[2][0], s[2][1]);
      bp1.wrd[1] = pk2bf(s[2][2], s[2][3]);
      bp1.wrd[2] = pk2bf(s[3][0], s[3][1]);
      bp1.wrd[3] = pk2bf(s[3][2], s[3][3]);

      __builtin_amdgcn_s_setprio(1);
#pragma unroll
      for (int dt = 0; dt < 4; ++dt) {
        o[qs][dt] = __builtin_amdgcn_mfma_f32_16x16x32_bf16(av[dt][0], bp0.f, o[qs][dt], 0, 0, 0);
        o[qs][dt] = __builtin_amdgcn_mfma_f32_16x16x32_bf16(av[dt][1], bp1.f, o[qs][dt], 0, 0, 0);
      }
      den[qs] = __builtin_amdgcn_mfma_f32_16x16x32_bf16(ones, bp0.f, den[qs], 0, 0, 0);
      den[qs] = __builtin_amdgcn_mfma_f32_16x16x32_bf16(ones, bp1.f, den[qs], 0, 0, 0);
      __builtin_amdgcn_s_setprio(0);
    }
  }

  // epilogue: every lane already holds its q-column's denominator (col=l16)
#pragma unroll
  for (int qs = 0; qs < 2; ++qs) {
    const float inv = 1.0f / den[qs][0];
    u16* orow = qk + (size_t)(b * NSEQ + qt * 128 + (w * 2 + qs) * 16 + l16) * 2048 + h * HDIM;
#pragma unroll
    for (int dt = 0; dt < 4; ++dt) {
      uint2 st;
      st.x = pk2bf(o[qs][dt][0] * inv, o[qs][dt][1] * inv);
      st.y = pk2bf(o[qs][dt][2] * inv, o[qs][dt][3] * inv);
      *(uint2*)(orow + dt * 16 + quad * 4) = st;
    }
  }
}

// ---------------------------------------------------------------- launch

extern "C" void kernel_launch(void* const* d_in, const int* in_sizes, int n_in,
                              void* d_out, int out_size, void* d_ws, size_t ws_size,
                              hipStream_t stream) {
  const void* x          = d_in[0];
  const void* ctx_ppr    = d_in[1];
  const void* ctx_trust  = d_in[2];
  const void* W_in       = d_in[3];
  const void* b_in       = d_in[4];
  const void* W_out      = d_in[5];
  const void* b_out      = d_in[6];
  const void* lppr_alpha = d_in[7];
  const void* tscale     = d_in[8];

  char* ws = (char*)d_ws;
  u16* Wt    = (u16*)ws;  ws += (size_t)3072 * 1024 * 2;    //  6 MB  W_in^T bf16
  u16* WoT   = (u16*)ws;  ws += (size_t)1024 * 1024 * 2;    //  2 MB  W_out^T bf16
  u16* qk    = (u16*)ws;  ws += (size_t)8192 * 2048 * 2;    // 32 MB  [Q|K]; attn-out overwrites Q-plane
  u16* Vtg   = (u16*)ws;  ws += (size_t)64 * 64 * 2048 * 2; // 16 MB  gated V^T [b*16+h][d][n]
  u16* xb    = (u16*)ws;  ws += (size_t)8192 * 1024 * 2;    // 16 MB  x as bf16
  float* bin_f  = (float*)ws; ws += 3072 * 4;
  float* bout_f = (float*)ws; ws += 1024 * 4;
  float* gate   = (float*)ws; ws += (size_t)BATCH * NCTXC * 4;
  float* cbias  = (float*)ws; ws += (size_t)BATCH * NCTXC * 4;
  int*   flag   = (int*)ws;   ws += 64;

  detect_kernel<<<dim3(1), dim3(256), 0, stream>>>((const u16*)x, flag);
  cast_x_kernel<<<dim3(4096), dim3(256), 0, stream>>>(x, xb, flag);
  transpose_flex<<<dim3(96, 32), dim3(32, 8), 0, stream>>>(W_in, Wt, 1024, 3072, flag);
  transpose_flex<<<dim3(32, 32), dim3(32, 8), 0, stream>>>(W_out, WoT, 1024, 1024, flag);
  prep_small<<<dim3(24), dim3(256), 0, stream>>>(b_in, b_out, ctx_ppr, ctx_trust,
                                                 lppr_alpha, tscale,
                                                 bin_f, bout_f, gate, cbias, flag);
  // merged QK GEMM (1024 blocks) + V^T GEMM (512 blocks)
  gemm_qkvt<<<dim3(1536), dim3(256), 0, stream>>>(xb, Wt, bin_f, gate, qk, Vtg);
  // fused biased attention (128-q, XCD-swizzled, in-register P)
  attn_kernel<<<dim3(1024), dim3(256), 0, stream>>>(qk, Vtg, cbias);
  // output GEMM: [8192x1024 (lda 2048)] @ [1024x1024] (+b_out) -> d_out
  gemm_out<<<dim3(8, 64), dim3(256), 0, stream>>>(qk, WoT, bout_f, d_out, flag);
}

// Round 5
// 285.715 us; speedup vs baseline: 1.5812x; 1.0540x over previous
//
#include <hip/hip_runtime.h>
#include <hip/hip_bf16.h>
#include <stdint.h>

// Problem constants: B=4, N=2048, D=1024, H=16, hd=64, NCTX=512
#define BATCH  4
#define NSEQ   2048
#define DMODEL 1024
#define NHEAD  16
#define HDIM   64
#define NCTXC  512

typedef unsigned short u16;
typedef __attribute__((ext_vector_type(8))) short bfrag;   // 8 bf16 = 4 VGPRs (MFMA A/B operand)
typedef __attribute__((ext_vector_type(4))) float facc;    // MFMA C/D operand

typedef __attribute__((address_space(3))) void lds_void;
typedef __attribute__((address_space(1))) void g_void;

__device__ __forceinline__ void gload16(const void* g, void* l) {
  __builtin_amdgcn_global_load_lds((const g_void*)g, (lds_void*)l, 16, 0, 0);
}

// bf16 conversion via HW v_cvt_pk_bf16_f32 (gfx950 has the instruction but no
// builtin — learn_hip m240). RNE rounding, same as the old bit-twiddle path.
__device__ __forceinline__ u16 f2bf(float f) {
  uint32_t r;
  asm("v_cvt_pk_bf16_f32 %0, %1, %1" : "=v"(r) : "v"(f));
  return (u16)r;
}

#if __has_builtin(__builtin_amdgcn_cvt_pk_bf16_f32)
__device__ __forceinline__ uint32_t pk2bf(float a, float b) {
  return __builtin_bit_cast(uint32_t, __builtin_amdgcn_cvt_pk_bf16_f32(a, b));
}
#else
__device__ __forceinline__ uint32_t pk2bf(float a, float b) {
  uint32_t r;
  asm("v_cvt_pk_bf16_f32 %0, %1, %2" : "=v"(r) : "v"(a), "v"(b));
  return r;
}
#endif

__device__ __forceinline__ float bf2f(u16 h) {
  union { uint32_t u; float f; } un;
  un.u = ((uint32_t)h) << 16;
  return un.f;
}

__device__ __forceinline__ float load_flex(const void* p, size_t idx, int isb) {
  return isb ? bf2f(((const u16*)p)[idx]) : ((const float*)p)[idx];
}

__device__ __forceinline__ uint4 pack8(float4 a, float4 b) {
  uint4 r;
  r.x = pk2bf(a.x, a.y);
  r.y = pk2bf(a.z, a.w);
  r.z = pk2bf(b.x, b.y);
  r.w = pk2bf(b.z, b.w);
  return r;
}

// ---------------------------------------------------------------- dtype detector
__global__ __launch_bounds__(256) void detect_kernel(const u16* __restrict__ xraw,
                                                     int* __restrict__ flag) {
  __shared__ int s_high, s_zero;
  if (threadIdx.x == 0) { s_high = 0; s_zero = 0; }
  __syncthreads();
  int h = 0, z = 0;
  for (int i = threadIdx.x; i < 4096; i += 256) {
    const u16 v = xraw[2 * i];
    const int e = (v >> 7) & 0xFF;
    if (e >= 0x90) h++;
    if (v == 0) z++;
  }
  atomicAdd(&s_high, h);
  atomicAdd(&s_zero, z);
  __syncthreads();
  if (threadIdx.x == 0) flag[0] = (s_high < 64 && s_zero < 2048) ? 1 : 0;
}

// ---------------------------------------------------------------- prep kernels

__global__ __launch_bounds__(256) void cast_x_kernel(const void* __restrict__ x,
                                                     u16* __restrict__ xb,
                                                     const int* __restrict__ flag) {
  const int isb = flag[0];
  const int i = blockIdx.x * 256 + threadIdx.x;
  if (isb) {
    ((uint4*)xb)[i] = ((const uint4*)x)[i];
  } else {
    const float4 f0 = ((const float4*)x)[2 * i];
    const float4 f1 = ((const float4*)x)[2 * i + 1];
    ((uint4*)xb)[i] = pack8(f0, f1);
  }
}

__global__ __launch_bounds__(256) void transpose_flex(const void* __restrict__ W,
                                                      u16* __restrict__ Wt,
                                                      int R, int C,
                                                      const int* __restrict__ flag) {
  __shared__ float tile[32][33];
  const int isb = flag[0];
  const int tx = threadIdx.x;
  const int ty = threadIdx.y;
  const int c0 = blockIdx.x * 32;
  const int r0 = blockIdx.y * 32;
#pragma unroll
  for (int j = 0; j < 32; j += 8)
    tile[ty + j][tx] = load_flex(W, (size_t)(r0 + ty + j) * C + c0 + tx, isb);
  __syncthreads();
#pragma unroll
  for (int j = 0; j < 32; j += 8)
    Wt[(size_t)(c0 + ty + j) * R + r0 + tx] = f2bf(tile[tx][ty + j]);
}

// fused small preps; cbias pre-scaled by log2(e) for exp2-domain softmax
__global__ __launch_bounds__(256) void prep_small(const void* __restrict__ b_in,
                                                  const void* __restrict__ b_out,
                                                  const void* __restrict__ ppr,
                                                  const void* __restrict__ trust,
                                                  const void* __restrict__ alpha_p,
                                                  const void* __restrict__ ts_p,
                                                  float* __restrict__ bin_f,
                                                  float* __restrict__ bout_f,
                                                  float* __restrict__ gate,
                                                  float* __restrict__ cbias,
                                                  const int* __restrict__ flag) {
  const int isb = flag[0];
  const int i = blockIdx.x * 256 + threadIdx.x;
  if (i < 3072) {
    bin_f[i] = load_flex(b_in, i, isb);
  } else if (i < 4096) {
    bout_f[i - 3072] = load_flex(b_out, i - 3072, isb);
  } else if (i < 4096 + BATCH * NCTXC) {
    const int j = i - 4096;
    const float ts = load_flex(ts_p, 0, isb), al = load_flex(alpha_p, 0, isb);
    gate[j]  = 1.0f / (1.0f + __expf(-ts * load_flex(trust, j, isb)));
    cbias[j] = -al * logf(fmaxf(load_flex(ppr, j, isb), 1e-8f)) * 1.44269504f;
  }
}

// ---------------------------------------------------------------- shared K-loop (m97 staging)
__device__ __forceinline__ void kloop_mfma(const u16* __restrict__ Ag,
                                           const u16* __restrict__ Bg,
                                           u16* As, u16* Bs,
                                           int tid, int wM, int wN, int l16, int quad,
                                           facc acc[4][4]) {
  char* ldsA = (char*)As + tid * 16;
  char* ldsB = (char*)Bs + tid * 16;
  for (int k0 = 0; k0 < 1024; k0 += 32) {
    __syncthreads();
    gload16(Ag + k0, ldsA);
    gload16(Ag + (size_t)64 * 1024 + k0, ldsA + 4096);
    gload16(Bg + k0, ldsB);
    gload16(Bg + (size_t)64 * 1024 + k0, ldsB + 4096);
    __syncthreads();

    bfrag af[4], bf[4];
#pragma unroll
    for (int i = 0; i < 4; ++i)
      af[i] = *(const bfrag*)(&As[(wM + i * 16 + l16) * 32 + quad * 8]);
#pragma unroll
    for (int j = 0; j < 4; ++j)
      bf[j] = *(const bfrag*)(&Bs[(wN + j * 16 + l16) * 32 + quad * 8]);
#pragma unroll
    for (int i = 0; i < 4; ++i)
#pragma unroll
      for (int j = 0; j < 4; ++j)
        acc[i][j] = __builtin_amdgcn_mfma_f32_16x16x32_bf16(af[i], bf[j], acc[i][j], 0, 0, 0);
  }
}

// ---------------------------------------------------------------- merged QK + V^T GEMM
__global__ __launch_bounds__(256) void gemm_qkvt(const u16* __restrict__ xb,
                                                 const u16* __restrict__ Wt,
                                                 const float* __restrict__ bin_f,
                                                 const float* __restrict__ gate,
                                                 u16* __restrict__ qk,
                                                 u16* __restrict__ Vtg) {
  __shared__ u16 As[128 * 32];
  __shared__ u16 Bs[128 * 32];
  const int tid  = threadIdx.x;
  const int w    = tid >> 6;
  const int lane = tid & 63;
  const int quad = lane >> 4;
  const int l16  = lane & 15;
  const int wM   = (w >> 1) * 64;
  const int wN   = (w & 1) * 64;
  const int id   = blockIdx.x;
  const int srow  = tid >> 2;
  const int spart = tid & 3;

  facc acc[4][4] = {};

  if (id < 1024) {
    const int bn = id & 15, bm = id >> 4;
    const u16* Ag = xb + (size_t)(bm * 128 + srow) * 1024 + spart * 8;
    const u16* Bg = Wt + (size_t)(bn * 128 + srow) * 1024 + spart * 8;
    kloop_mfma(Ag, Bg, As, Bs, tid, wM, wN, l16, quad, acc);

    const float qs = (bn < 8) ? 0.18033688f : 1.0f;
#pragma unroll
    for (int i = 0; i < 4; ++i) {
      const int grow0 = bm * 128 + wM + i * 16 + quad * 4;
#pragma unroll
      for (int j = 0; j < 4; ++j) {
        const int gcol = bn * 128 + wN + j * 16 + l16;
        const float bv = bin_f[gcol];
#pragma unroll
        for (int r = 0; r < 4; ++r)
          qk[(size_t)(grow0 + r) * 2048 + gcol] = f2bf((acc[i][j][r] + bv) * qs);
      }
    }
  } else {
    const int id2 = id - 1024;
    const int bn = id2 & 63, bm = id2 >> 6;
    const u16* Ag = Wt + (size_t)2048 * 1024 + (size_t)(bm * 128 + srow) * 1024 + spart * 8;
    const u16* Bg = xb + (size_t)(bn * 128 + srow) * 1024 + spart * 8;
    kloop_mfma(Ag, Bg, As, Bs, tid, wM, wN, l16, quad, acc);

#pragma unroll
    for (int i = 0; i < 4; ++i) {
      const int grow0 = bm * 128 + wM + i * 16 + quad * 4;
      const int h   = grow0 >> 6;
      const int dd0 = grow0 & 63;
#pragma unroll
      for (int j = 0; j < 4; ++j) {
        const int gcol = bn * 128 + wN + j * 16 + l16;
        const int bb  = gcol >> 11;
        const int tok = gcol & (NSEQ - 1);
        const float gl = (tok < NCTXC) ? gate[bb * NCTXC + tok] : 1.0f;
        u16* dst = &Vtg[((size_t)((bb * NHEAD + h) * HDIM + dd0)) * NSEQ + tok];
#pragma unroll
        for (int r = 0; r < 4; ++r)
          dst[(size_t)r * NSEQ] = f2bf((acc[i][j][r] + bin_f[2 * DMODEL + grow0 + r]) * gl);
      }
    }
  }
}

// ---------------------------------------------------------------- output GEMM (m97 staging)
__global__ __launch_bounds__(256) void gemm_out(const u16* __restrict__ A,
                                                const u16* __restrict__ Bt,
                                                const float* __restrict__ biasf,
                                                void* __restrict__ Cout,
                                                const int* __restrict__ flag) {
  __shared__ u16 As[128 * 32];
  __shared__ u16 Bs[128 * 32];
  const int isb  = flag[0];
  const int tid  = threadIdx.x;
  const int w    = tid >> 6;
  const int lane = tid & 63;
  const int quad = lane >> 4;
  const int l16  = lane & 15;
  const int wM   = (w >> 1) * 64;
  const int wN   = (w & 1) * 64;
  const int bm   = blockIdx.y;
  const int bn   = blockIdx.x;
  const int srow  = tid >> 2;
  const int spart = tid & 3;

  facc acc[4][4] = {};
  const u16* Ag = A + (size_t)(bm * 128 + srow) * 2048 + spart * 8;
  const u16* Bg = Bt + (size_t)(bn * 128 + srow) * 1024 + spart * 8;
  char* ldsA = (char*)As + tid * 16;
  char* ldsB = (char*)Bs + tid * 16;

  for (int k0 = 0; k0 < 1024; k0 += 32) {
    __syncthreads();
    gload16(Ag + k0, ldsA);
    gload16(Ag + (size_t)64 * 2048 + k0, ldsA + 4096);
    gload16(Bg + k0, ldsB);
    gload16(Bg + (size_t)64 * 1024 + k0, ldsB + 4096);
    __syncthreads();

    bfrag af[4], bf[4];
#pragma unroll
    for (int i = 0; i < 4; ++i)
      af[i] = *(const bfrag*)(&As[(wM + i * 16 + l16) * 32 + quad * 8]);
#pragma unroll
    for (int j = 0; j < 4; ++j)
      bf[j] = *(const bfrag*)(&Bs[(wN + j * 16 + l16) * 32 + quad * 8]);
#pragma unroll
    for (int i = 0; i < 4; ++i)
#pragma unroll
      for (int j = 0; j < 4; ++j)
        acc[i][j] = __builtin_amdgcn_mfma_f32_16x16x32_bf16(af[i], bf[j], acc[i][j], 0, 0, 0);
  }

#pragma unroll
  for (int i = 0; i < 4; ++i) {
    const int grow0 = bm * 128 + wM + i * 16 + quad * 4;
#pragma unroll
    for (int j = 0; j < 4; ++j) {
      const int gcol = bn * 128 + wN + j * 16 + l16;
      const float bv = biasf[gcol];
#pragma unroll
      for (int r = 0; r < 4; ++r) {
        const float v = acc[i][j][r] + bv;
        if (isb) ((u16*)Cout)[(size_t)(grow0 + r) * 1024 + gcol] = f2bf(v);
        else     ((float*)Cout)[(size_t)(grow0 + r) * 1024 + gcol] = v;
      }
    }
  }
}

// ---------------------------------------------------------------- flash attention
// R5: 2 waves × 64 q each (128-q blocks, grid unchanged). K/V fragment reads
// are per (wave, kv-tile) — doubling q per wave HALVES LDS reads per FLOP and
// gives 4 independent QK→exp→PV chains per wave. Staging via global_load_lds
// into a double-buffered LINEAR [64][64] tile with m201-style both-sides XOR
// swizzle (chunk (c&7)^(row&7) on the per-lane GLOBAL source, same XOR on the
// LDS fragment reads). One __syncthreads per tile (its implicit vmcnt(0)
// drains the DMA). In-register P (R4's verified k-order mapping) unchanged.
__global__ __launch_bounds__(128, 2) void attn_kernel(u16* __restrict__ qk,
                                                      const u16* __restrict__ vtg,
                                                      const float* __restrict__ cbias) {
  const int id    = blockIdx.x;             // 0..1023
  const int chunk = id >> 3;
  const int qt    = chunk & 15;
  const int hg    = (id & 7) | ((chunk >> 4) << 3);
  const int h     = hg & 15;
  const int b     = hg >> 4;

  __shared__ u16 KV[2][2][64 * 64];  // [buf][K|V][row*64+col], linear, src-swizzled

  const int tid  = threadIdx.x;      // 0..127
  const int w    = tid >> 6;         // 0..1
  const int lane = tid & 63;
  const int quad = lane >> 4;
  const int l16  = lane & 15;

  // Q: wave w owns q rows qt*128 + w*64 + qs*16 + l16, qs = 0..3
  bfrag bq[4][2];
#pragma unroll
  for (int qs = 0; qs < 4; ++qs) {
    const u16* qrow = qk + (size_t)(b * NSEQ + qt * 128 + w * 64 + qs * 16 + l16) * 2048 + h * HDIM;
    bq[qs][0] = *(const bfrag*)(qrow + quad * 8);
    bq[qs][1] = *(const bfrag*)(qrow + 32 + quad * 8);
  }

  // ones A-fragment for the denominator MFMA (k-order invariant)
  bfrag ones;
#pragma unroll
  for (int i = 0; i < 8; ++i) ones[i] = (short)0x3F80;   // bf16 1.0

  facc den[4] = {};
  facc o[4][4] = {};

  const u16* kbase = qk + (size_t)(b * NSEQ) * 2048 + DMODEL + h * HDIM;
  const u16* vbase = vtg + (size_t)((b * NHEAD + h) * HDIM) * NSEQ;

  // staging chunk map: chunk c = tid + i*128 → row c>>3, swizzled 16B-slot (c&7)^(row&7)
  int crow[4], csc[4];
#pragma unroll
  for (int i = 0; i < 4; ++i) {
    const int c = tid + i * 128;
    crow[i] = c >> 3;
    csc[i]  = (c & 7) ^ (crow[i] & 7);
  }

  // read-side swizzle constants (elem offsets)
  const int e    = l16 & 7;
  const int swk0 = (quad ^ e) * 8;                 // K half-0 chunk
  const int cA0  = ((quad >> 1) ^ e) * 8 + (quad & 1) * 4;  // V base (qb folded in)

  auto stage = [&](int sel, int t) {
#pragma unroll
    for (int i = 0; i < 4; ++i) {
      const int c = tid + i * 128;
      gload16(kbase + (size_t)(t * 64 + crow[i]) * 2048 + csc[i] * 8, &KV[sel][0][c * 8]);
      gload16(vbase + (size_t)crow[i] * 2048 + t * 64 + csc[i] * 8,   &KV[sel][1][c * 8]);
    }
  };

  stage(0, 0);

  for (int t = 0; t < NSEQ / 64; ++t) {
    __syncthreads();                 // drains own gloads (implicit vmcnt(0)) + barrier
    if (t + 1 < NSEQ / 64) stage((t + 1) & 1, t + 1);   // writes the OTHER buffer

    const u16* Kb = KV[t & 1][0];
    const u16* Vb = KV[t & 1][1];

    // K fragments (swizzled b128)
    bfrag ak[4][2];
#pragma unroll
    for (int nt = 0; nt < 4; ++nt) {
      const u16* kr = &Kb[(nt * 16 + l16) * 64];
      ak[nt][0] = *(const bfrag*)(kr + swk0);
      ak[nt][1] = *(const bfrag*)(kr + (swk0 ^ 32));
    }

    // V fragments in the bp-matching k-order (swizzled b64 pairs):
    // av[dt][half] elem j = V^T[dt*16+l16][ half*32 + (j>>2)*16 + quad*4 + (j&3) ]
    bfrag av[4][2];
#pragma unroll
    for (int dt = 0; dt < 4; ++dt) {
      const u16* vr = &Vb[(dt * 16 + l16) * 64];
      union { bfrag f; uint2 u2[2]; } un0, un1;
      un0.u2[0] = *(const uint2*)(vr + cA0);
      un0.u2[1] = *(const uint2*)(vr + (cA0 ^ 16));
      un1.u2[0] = *(const uint2*)(vr + (cA0 ^ 32));
      un1.u2[1] = *(const uint2*)(vr + (cA0 ^ 48));
      av[dt][0] = un0.f;
      av[dt][1] = un1.f;
    }

    // per-tile column bias as MFMA C-init (kv-only, shared by all qs)
    facc zb[4];
    if (t < 8) {
      const float* cb = cbias + b * NCTXC + t * 64 + quad * 4;
#pragma unroll
      for (int nt = 0; nt < 4; ++nt) zb[nt] = *(const facc*)(cb + nt * 16);
    } else {
#pragma unroll
      for (int nt = 0; nt < 4; ++nt) zb[nt] = (facc){};
    }

    // 4 q-subtiles: QK -> exp2 -> in-register pack -> PV + den
#pragma unroll
    for (int qs = 0; qs < 4; ++qs) {
      facc s[4];
      __builtin_amdgcn_s_setprio(1);
#pragma unroll
      for (int nt = 0; nt < 4; ++nt) {
        facc z = zb[nt];
        z = __builtin_amdgcn_mfma_f32_16x16x32_bf16(ak[nt][0], bq[qs][0], z, 0, 0, 0);
        s[nt] = __builtin_amdgcn_mfma_f32_16x16x32_bf16(ak[nt][1], bq[qs][1], z, 0, 0, 0);
      }
      __builtin_amdgcn_s_setprio(0);

#pragma unroll
      for (int nt = 0; nt < 4; ++nt)
#pragma unroll
        for (int r = 0; r < 4; ++r)
          s[nt][r] = __builtin_amdgcn_exp2f(s[nt][r]);

      // bp[half] slot j holds P[kv = half*32 + (j>>2)*16 + quad*4 + (j&3)][l16]
      union { bfrag f; uint32_t wrd[4]; } bp0, bp1;
      bp0.wrd[0] = pk2bf(s[0][0], s[0][1]);
      bp0.wrd[1] = pk2bf(s[0][2], s[0][3]);
      bp0.wrd[2] = pk2bf(s[1][0], s[1][1]);
      bp0.wrd[3] = pk2bf(s[1][2], s[1][3]);
      bp1.wrd[0] = pk2bf(s[2][0], s[2][1]);
      bp1.wrd[1] = pk2bf(s[2][2], s[2][3]);
      bp1.wrd[2] = pk2bf(s[3][0], s[3][1]);
      bp1.wrd[3] = pk2bf(s[3][2], s[3][3]);

      __builtin_amdgcn_s_setprio(1);
#pragma unroll
      for (int dt = 0; dt < 4; ++dt) {
        o[qs][dt] = __builtin_amdgcn_mfma_f32_16x16x32_bf16(av[dt][0], bp0.f, o[qs][dt], 0, 0, 0);
        o[qs][dt] = __builtin_amdgcn_mfma_f32_16x16x32_bf16(av[dt][1], bp1.f, o[qs][dt], 0, 0, 0);
      }
      den[qs] = __builtin_amdgcn_mfma_f32_16x16x32_bf16(ones, bp0.f, den[qs], 0, 0, 0);
      den[qs] = __builtin_amdgcn_mfma_f32_16x16x32_bf16(ones, bp1.f, den[qs], 0, 0, 0);
      __builtin_amdgcn_s_setprio(0);
    }
  }

  // epilogue: every lane holds its q-column's denominator at den[qs][0]
#pragma unroll
  for (int qs = 0; qs < 4; ++qs) {
    const float inv = 1.0f / den[qs][0];
    u16* orow = qk + (size_t)(b * NSEQ + qt * 128 + w * 64 + qs * 16 + l16) * 2048 + h * HDIM;
#pragma unroll
    for (int dt = 0; dt < 4; ++dt) {
      uint2 st;
      st.x = pk2bf(o[qs][dt][0] * inv, o[qs][dt][1] * inv);
      st.y = pk2bf(o[qs][dt][2] * inv, o[qs][dt][3] * inv);
      *(uint2*)(orow + dt * 16 + quad * 4) = st;
    }
  }
}

// ---------------------------------------------------------------- launch

extern "C" void kernel_launch(void* const* d_in, const int* in_sizes, int n_in,
                              void* d_out, int out_size, void* d_ws, size_t ws_size,
                              hipStream_t stream) {
  const void* x          = d_in[0];
  const void* ctx_ppr    = d_in[1];
  const void* ctx_trust  = d_in[2];
  const void* W_in       = d_in[3];
  const void* b_in       = d_in[4];
  const void* W_out      = d_in[5];
  const void* b_out      = d_in[6];
  const void* lppr_alpha = d_in[7];
  const void* tscale     = d_in[8];

  char* ws = (char*)d_ws;
  u16* Wt    = (u16*)ws;  ws += (size_t)3072 * 1024 * 2;    //  6 MB  W_in^T bf16
  u16* WoT   = (u16*)ws;  ws += (size_t)1024 * 1024 * 2;    //  2 MB  W_out^T bf16
  u16* qk    = (u16*)ws;  ws += (size_t)8192 * 2048 * 2;    // 32 MB  [Q|K]; attn-out overwrites Q-plane
  u16* Vtg   = (u16*)ws;  ws += (size_t)64 * 64 * 2048 * 2; // 16 MB  gated V^T [b*16+h][d][n]
  u16* xb    = (u16*)ws;  ws += (size_t)8192 * 1024 * 2;    // 16 MB  x as bf16
  float* bin_f  = (float*)ws; ws += 3072 * 4;
  float* bout_f = (float*)ws; ws += 1024 * 4;
  float* gate   = (float*)ws; ws += (size_t)BATCH * NCTXC * 4;
  float* cbias  = (float*)ws; ws += (size_t)BATCH * NCTXC * 4;
  int*   flag   = (int*)ws;   ws += 64;

  detect_kernel<<<dim3(1), dim3(256), 0, stream>>>((const u16*)x, flag);
  cast_x_kernel<<<dim3(4096), dim3(256), 0, stream>>>(x, xb, flag);
  transpose_flex<<<dim3(96, 32), dim3(32, 8), 0, stream>>>(W_in, Wt, 1024, 3072, flag);
  transpose_flex<<<dim3(32, 32), dim3(32, 8), 0, stream>>>(W_out, WoT, 1024, 1024, flag);
  prep_small<<<dim3(24), dim3(256), 0, stream>>>(b_in, b_out, ctx_ppr, ctx_trust,
                                                 lppr_alpha, tscale,
                                                 bin_f, bout_f, gate, cbias, flag);
  // merged QK GEMM (1024 blocks) + V^T GEMM (512 blocks)
  gemm_qkvt<<<dim3(1536), dim3(256), 0, stream>>>(xb, Wt, bin_f, gate, qk, Vtg);
  // fused biased attention (128-q, XCD-swizzled, 2 waves × 64 q, gload_lds dbuf)
  attn_kernel<<<dim3(1024), dim3(128), 0, stream>>>(qk, Vtg, cbias);
  // output GEMM: [8192x1024 (lda 2048)] @ [1024x1024] (+b_out) -> d_out
  gemm_out<<<dim3(8, 64), dim3(256), 0, stream>>>(qk, WoT, bout_f, d_out, flag);
}